// Round 1
// 313.571 us; speedup vs baseline: 1.1976x; 1.1976x over previous
//
#include <hip/hip_runtime.h>
#include <hip/hip_bf16.h>

// B=16, S=2048, D=64 attention w/ symmetric pad mask.
// out = [context (B*S*D fp32), attn (B*S*S fp32)] concatenated.
//
// R5: staging overhaul. R4 was phase-serialization-bound: per-panel fp32->bf16
// convert + register round-trip + in-kernel V transpose + full-drain barriers.
// Now: one-shot pre-pass converts K->bf16 and V->V^T bf16 into d_ws with the
// LDS bank swizzle PRE-APPLIED in the global layout (global_load_lds writes
// linearly -> source must carry the permutation). Main kernel stages panels
// with global_load_lds width=16 (no VALU, no reg round-trip, bf16 halves L2
// bytes), pass A double-buffers K (stage next / compute cur / syncthreads),
// pass B issues next-panel staging under the attn copy-out phase. Column mask
// preloaded once; 1/sqrt(64) folded into Q pack (exact pow2, bit-identical).
// Falls back to the verified R4 kernel if ws_size < 8 MB.
#define NBATCH 16
#define SLEN   2048
#define DIM    64
#define TQ     64
#define NTHR   256
#define NW     4
#define PANEL  128
#define NPANEL (SLEN / PANEL)   // 16
#define PROWP  136              // shorts: 128 data + 8 pad (16B-aligned rows)
// fallback (R4) layout constants
#define PROWK  72
#define PROWV  136

typedef __attribute__((ext_vector_type(8))) short bf16x8;
typedef __attribute__((ext_vector_type(4))) float f32x4;

__device__ inline short f2bf(float f) {
    union { __hip_bfloat16 h; short s; } u;
    u.h = __float2bfloat16(f);
    return u.s;
}
__device__ inline float bf2f(unsigned short s) {
    union { unsigned u; float f; } x;
    x.u = ((unsigned)s) << 16;
    return x.f;
}
__device__ inline bf16x8 pack8(float4 a, float4 b) {
    bf16x8 r;
    r[0] = f2bf(a.x); r[1] = f2bf(a.y); r[2] = f2bf(a.z); r[3] = f2bf(a.w);
    r[4] = f2bf(b.x); r[5] = f2bf(b.y); r[6] = f2bf(b.z); r[7] = f2bf(b.w);
    return r;
}
__device__ inline bf16x8 pack8s(float4 a, float4 b, float s) {
    bf16x8 r;
    r[0] = f2bf(a.x * s); r[1] = f2bf(a.y * s); r[2] = f2bf(a.z * s); r[3] = f2bf(a.w * s);
    r[4] = f2bf(b.x * s); r[5] = f2bf(b.y * s); r[6] = f2bf(b.z * s); r[7] = f2bf(b.w * s);
    return r;
}

// ---------------- pre-pass: K -> bf16 swizzled, V -> V^T bf16 swizzled ----
// Kws[b][j][.]: row j's 8 16B-blocks stored at blk ^ (j&7)  (64 shorts/row)
// VTws[b][d][.]: within each 128-col panel, 16B-quad q stored at q ^ (d&7)
__global__ __launch_bounds__(256) void preconvert_kernel(
    const float* __restrict__ K, const float* __restrict__ V,
    short* __restrict__ Kws, short* __restrict__ VTws)
{
    const int b  = blockIdx.x >> 4;      // NPANEL=16
    const int p  = blockIdx.x & 15;
    const int j0 = p * PANEL;
    const int tid = threadIdx.x;
    const float* Kb = K + ((size_t)b * SLEN + j0) * DIM;
    const float* Vb = V + ((size_t)b * SLEN + j0) * DIM;
    short* Kwb  = Kws  + ((size_t)b * SLEN + j0) * DIM;
    short* VTwb = VTws + (size_t)b * DIM * SLEN;

    #pragma unroll
    for (int it = 0; it < 8; it++) {           // K: 128 rows x 16 float4
        const int idx = it * 256 + tid;
        const int row = idx >> 4, c4 = idx & 15;
        float4 kv = *(const float4*)(Kb + (size_t)row * DIM + c4 * 4);
        const int blk = (c4 >> 1) ^ (row & 7); // natural block c4>>1, swizzled
        *(short4*)(Kwb + (size_t)row * DIM + blk * 8 + (c4 & 1) * 4) =
            make_short4(f2bf(kv.x), f2bf(kv.y), f2bf(kv.z), f2bf(kv.w));
    }
    #pragma unroll
    for (int it = 0; it < 2; it++) {           // V: 4k x 4d register transpose
        const int task = it * 256 + tid;
        const int k4 = task >> 4, d4 = (task & 15) * 4;
        const int kb = k4 * 4;
        const float* vp = Vb + (size_t)kb * DIM + d4;
        float4 r0 = *(const float4*)(vp);
        float4 r1 = *(const float4*)(vp + DIM);
        float4 r2 = *(const float4*)(vp + 2 * DIM);
        float4 r3 = *(const float4*)(vp + 3 * DIM);
        const int qn = kb >> 3, hw = kb & 7;   // natural quad, half offset (0/4)
        *(short4*)(VTwb + (size_t)(d4 + 0) * SLEN + j0 + ((qn ^ ((d4 + 0) & 7)) * 8) + hw) =
            make_short4(f2bf(r0.x), f2bf(r1.x), f2bf(r2.x), f2bf(r3.x));
        *(short4*)(VTwb + (size_t)(d4 + 1) * SLEN + j0 + ((qn ^ ((d4 + 1) & 7)) * 8) + hw) =
            make_short4(f2bf(r0.y), f2bf(r1.y), f2bf(r2.y), f2bf(r3.y));
        *(short4*)(VTwb + (size_t)(d4 + 2) * SLEN + j0 + ((qn ^ ((d4 + 2) & 7)) * 8) + hw) =
            make_short4(f2bf(r0.z), f2bf(r1.z), f2bf(r2.z), f2bf(r3.z));
        *(short4*)(VTwb + (size_t)(d4 + 3) * SLEN + j0 + ((qn ^ ((d4 + 3) & 7)) * 8) + hw) =
            make_short4(f2bf(r0.w), f2bf(r1.w), f2bf(r2.w), f2bf(r3.w));
    }
}

// ---- async staging: linear LDS copy (swizzle already in global layout) ----
__device__ __forceinline__ void stage_k_panel(const short* __restrict__ Kwb, int j0,
                                              short* sdst, int w, int l) {
    const short* src = Kwb + (size_t)j0 * DIM + w * 512 + l * 8;  // per-lane
    short* dst = sdst + w * 512;                                  // wave-uniform
    #pragma unroll
    for (int i = 0; i < 4; i++)
        __builtin_amdgcn_global_load_lds((const unsigned int*)(src + i * 2048),
                                         (unsigned int*)(dst + i * 2048), 16, 0, 0);
}
__device__ __forceinline__ void stage_v_panel(const short* __restrict__ VTwb, int j0,
                                              short* sdst, int w, int l) {
    #pragma unroll
    for (int i = 0; i < 4; i++) {
        const int d0 = (w * 4 + i) * 4;                           // 4 rows/chunk
        __builtin_amdgcn_global_load_lds(
            (const unsigned int*)(VTwb + (size_t)(d0 + (l >> 4)) * SLEN + j0 + (l & 15) * 8),
            (unsigned int*)(sdst + d0 * PANEL), 16, 0, 0);        // wave-uniform base
    }
}

#define MFMA16(a, bb, cc) __builtin_amdgcn_mfma_f32_16x16x32_bf16((a), (bb), (cc), 0, 0, 0)

__global__ __launch_bounds__(NTHR, 2) void sdpa_kernel(
    const float* __restrict__ Q, const short* __restrict__ Kws,
    const short* __restrict__ VTws, const int* __restrict__ M,
    float* __restrict__ outCtx, float* __restrict__ outAttn)
{
    __shared__ __align__(16) short sK[PANEL * DIM];     // 16 KB K panel (linear+preswz)
    __shared__ __align__(16) short sVT[DIM * PANEL];    // 16 KB V^T panel / passA K buf1
    __shared__ __align__(16) short sP[NW * 16 * PROWP]; // 17 KB per-wave P
    __shared__ float sMaskAll[SLEN];                    // 8 KB column mask 0/1

    const int tid = threadIdx.x;
    const int w = tid >> 6, l = tid & 63, g = l >> 4, c = l & 15;
    const int b  = blockIdx.x >> 5;          // 32 blocks/batch
    const int i0 = (blockIdx.x & 31) * TQ;
    const int i0w = i0 + w * 16;

    const short* Kwb  = Kws  + (size_t)b * SLEN * DIM;
    const short* VTwb = VTws + (size_t)b * DIM * SLEN;
    const int*   Mb   = M + b * SLEN;

    // Q A-frags, pre-scaled by 1/sqrt(64)=2^-3 (exact; bit-identical scores)
    bf16x8 qa0, qa1;
    {
        const float* qp = Q + ((size_t)b * SLEN + i0w + c) * DIM + g * 8;
        qa0 = pack8s(*(const float4*)(qp),      *(const float4*)(qp + 4),  0.125f);
        qa1 = pack8s(*(const float4*)(qp + 32), *(const float4*)(qp + 36), 0.125f);
    }

    #pragma unroll
    for (int i = 0; i < 8; i++)
        sMaskAll[i * NTHR + tid] = Mb[i * NTHR + tid] ? 0.f : 1.f;
    stage_k_panel(Kwb, 0, sK, w, l);
    __syncthreads();

    // ---- Pass A: row sums, K double-buffered across sK/sVT ----
    float rsum[4] = {0.f, 0.f, 0.f, 0.f};
    for (int p = 0; p < NPANEL; p++) {
        const short* cur = (p & 1) ? sVT : sK;
        if (p < NPANEL - 1)
            stage_k_panel(Kwb, (p + 1) * PANEL, (p & 1) ? sK : sVT, w, l);
        const int j0 = p * PANEL;
        #pragma unroll
        for (int jt = 0; jt < 8; jt++) {
            const short* kr = cur + (jt * 16 + c) * DIM;
            bf16x8 kb0 = *(const bf16x8*)(kr + ((g ^ (c & 7)) * 8));
            bf16x8 kb1 = *(const bf16x8*)(kr + (((g + 4) ^ (c & 7)) * 8));
            f32x4 acc = {0.f, 0.f, 0.f, 0.f};
            acc = MFMA16(qa0, kb0, acc);
            acc = MFMA16(qa1, kb1, acc);
            const float em = sMaskAll[j0 + jt * 16 + c];
            #pragma unroll
            for (int r = 0; r < 4; r++)
                rsum[r] += __expf(acc[r]) * em;
        }
        __syncthreads();   // drains next-panel stage (flew under compute)
    }
    #pragma unroll
    for (int off = 1; off < 16; off <<= 1) {
        #pragma unroll
        for (int r = 0; r < 4; r++)
            rsum[r] += __shfl_xor(rsum[r], off, 64);
    }
    float scv[4];
    #pragma unroll
    for (int r = 0; r < 4; r++) {
        const float rm = sMaskAll[i0w + g * 4 + r];
        scv[r] = (rm == 0.f || rsum[r] <= 0.f) ? 0.f : 1.f / rsum[r];
    }

    // ---- Pass B: recompute, stage P, write attn, accumulate PV ----
    short* sPw = sP + w * 16 * PROWP;
    f32x4 pv[4];
    #pragma unroll
    for (int nt = 0; nt < 4; nt++) pv[nt] = (f32x4){0.f, 0.f, 0.f, 0.f};

    stage_k_panel(Kwb, 0, sK, w, l);
    stage_v_panel(VTwb, 0, sVT, w, l);
    __syncthreads();

    for (int p = 0; p < NPANEL; p++) {
        const int j0 = p * PANEL;
        // QK -> normalized P (bf16) in per-wave LDS panel
        #pragma unroll
        for (int jt = 0; jt < 8; jt++) {
            const short* kr = sK + (jt * 16 + c) * DIM;
            bf16x8 kb0 = *(const bf16x8*)(kr + ((g ^ (c & 7)) * 8));
            bf16x8 kb1 = *(const bf16x8*)(kr + (((g + 4) ^ (c & 7)) * 8));
            f32x4 acc = {0.f, 0.f, 0.f, 0.f};
            acc = MFMA16(qa0, kb0, acc);
            acc = MFMA16(qa1, kb1, acc);
            const float em = sMaskAll[j0 + jt * 16 + c];
            #pragma unroll
            for (int r = 0; r < 4; r++)
                sPw[(g * 4 + r) * PROWP + jt * 16 + c] =
                    f2bf(__expf(acc[r]) * em * scv[r]);
        }
        // PV: A-frag b128 from own P panel; B-frag b128 from swizzled V^T
        #pragma unroll
        for (int ks = 0; ks < 4; ks++) {
            bf16x8 af = *(const bf16x8*)(sPw + c * PROWP + ks * 32 + g * 8);
            #pragma unroll
            for (int nt = 0; nt < 4; nt++) {
                const int d = nt * 16 + c;
                bf16x8 bfrag = *(const bf16x8*)(sVT + d * PANEL + (((ks * 4 + g) ^ (d & 7)) * 8));
                pv[nt] = MFMA16(af, bfrag, pv[nt]);
            }
        }
        __syncthreads();   // all waves done with sK/sVT -> safe to restage
        if (p < NPANEL - 1) {
            stage_k_panel(Kwb, j0 + PANEL, sK, w, l);   // flies under attn write
            stage_v_panel(VTwb, j0 + PANEL, sVT, w, l);
        }
        // attn write: 16 rows x 32 float4, fully coalesced
        const size_t rowBase = (size_t)b * SLEN + i0w;
        #pragma unroll
        for (int it = 0; it < 8; it++) {
            const int idx = it * 64 + l;
            const int row = idx >> 5, col4 = idx & 31;
            const unsigned short* pp = (const unsigned short*)sPw + row * PROWP + col4 * 4;
            ushort4 p4 = *(const ushort4*)(pp);
            float4 o = {bf2f(p4.x), bf2f(p4.y), bf2f(p4.z), bf2f(p4.w)};
            *(float4*)(outAttn + (rowBase + row) * SLEN + j0 + col4 * 4) = o;
        }
        __syncthreads();   // drains stage loads (+ attn stores) before next panel
    }

    // ctx write: C-layout direct store (pre-normalized P => no further scale)
    #pragma unroll
    for (int nt = 0; nt < 4; nt++) {
        #pragma unroll
        for (int r = 0; r < 4; r++)
            outCtx[((size_t)b * SLEN + i0w + g * 4 + r) * DIM + nt * 16 + c] = pv[nt][r];
    }
}

// ---------------- fallback: verified R4 kernel (used if ws too small) -----
__global__ __launch_bounds__(NTHR, 3) void sdpa_kernel_fb(
    const float* __restrict__ Q, const float* __restrict__ K,
    const float* __restrict__ V, const int* __restrict__ M,
    float* __restrict__ outCtx, float* __restrict__ outAttn)
{
    __shared__ __align__(16) short sK[128 * PROWK];
    __shared__ __align__(16) short sVT[64 * PROWV];
    __shared__ __align__(16) short sP[NW * 16 * PROWP];
    __shared__ float sMask[PANEL];

    const int tid = threadIdx.x;
    const int w = tid >> 6, l = tid & 63, g = l >> 4, c = l & 15;
    const int b  = blockIdx.x >> 5;
    const int i0 = (blockIdx.x & 31) * TQ;
    const int i0w = i0 + w * 16;

    const float* Kb = K + (size_t)b * SLEN * DIM;
    const float* Vb = V + (size_t)b * SLEN * DIM;
    const int*   Mb = M + b * SLEN;

    bf16x8 qa0, qa1;
    {
        const float* qp = Q + ((size_t)b * SLEN + i0w + c) * DIM + g * 8;
        qa0 = pack8(*(const float4*)(qp),      *(const float4*)(qp + 4));
        qa1 = pack8(*(const float4*)(qp + 32), *(const float4*)(qp + 36));
    }

    const float scl = 0.125f;
    float rsum[4] = {0.f, 0.f, 0.f, 0.f};

    for (int p = 0; p < NPANEL; p++) {
        const int j0 = p * PANEL;
        #pragma unroll
        for (int it = 0; it < 8; it++) {
            const int idx = it * NTHR + tid;
            const int row = idx >> 4, c4 = idx & 15;
            float4 kv = *(const float4*)(Kb + (size_t)(j0 + row) * DIM + c4 * 4);
            *(short4*)(sK + row * PROWK + c4 * 4) =
                make_short4(f2bf(kv.x), f2bf(kv.y), f2bf(kv.z), f2bf(kv.w));
        }
        if (tid < PANEL) sMask[tid] = Mb[j0 + tid] ? 0.f : 1.f;
        __syncthreads();
        #pragma unroll
        for (int jt = 0; jt < 8; jt++) {
            const short* kr = sK + (jt * 16 + c) * PROWK + g * 8;
            bf16x8 kb0 = *(const bf16x8*)(kr);
            bf16x8 kb1 = *(const bf16x8*)(kr + 32);
            f32x4 acc = {0.f, 0.f, 0.f, 0.f};
            acc = MFMA16(qa0, kb0, acc);
            acc = MFMA16(qa1, kb1, acc);
            const float em = sMask[jt * 16 + c];
            #pragma unroll
            for (int r = 0; r < 4; r++)
                rsum[r] += __expf(acc[r] * scl) * em;
        }
        __syncthreads();
    }
    #pragma unroll
    for (int off = 1; off < 16; off <<= 1) {
        #pragma unroll
        for (int r = 0; r < 4; r++)
            rsum[r] += __shfl_xor(rsum[r], off, 64);
    }
    float scv[4];
    #pragma unroll
    for (int r = 0; r < 4; r++) {
        const int rm = Mb[i0w + g * 4 + r];
        scv[r] = (rm || rsum[r] <= 0.f) ? 0.f : 1.f / rsum[r];
    }

    short* sPw = sP + w * 16 * PROWP;
    f32x4 pv[4];
    #pragma unroll
    for (int nt = 0; nt < 4; nt++) pv[nt] = (f32x4){0.f, 0.f, 0.f, 0.f};

    for (int p = 0; p < NPANEL; p++) {
        const int j0 = p * PANEL;
        #pragma unroll
        for (int it = 0; it < 8; it++) {
            const int idx = it * NTHR + tid;
            const int row = idx >> 4, c4 = idx & 15;
            float4 kv = *(const float4*)(Kb + (size_t)(j0 + row) * DIM + c4 * 4);
            *(short4*)(sK + row * PROWK + c4 * 4) =
                make_short4(f2bf(kv.x), f2bf(kv.y), f2bf(kv.z), f2bf(kv.w));
        }
        #pragma unroll
        for (int it = 0; it < 2; it++) {
            const int task = it * NTHR + tid;
            const int k4 = task >> 4, d4g = task & 15;
            const int kb = k4 * 4, d4 = d4g * 4;
            const int colb = kb ^ ((d4g & 3) << 3);
            const float* vp = Vb + (size_t)(j0 + kb) * DIM + d4;
            float4 r0 = *(const float4*)(vp);
            float4 r1 = *(const float4*)(vp + DIM);
            float4 r2 = *(const float4*)(vp + 2 * DIM);
            float4 r3 = *(const float4*)(vp + 3 * DIM);
            *(short4*)(sVT + (d4 + 0) * PROWV + colb) =
                make_short4(f2bf(r0.x), f2bf(r1.x), f2bf(r2.x), f2bf(r3.x));
            *(short4*)(sVT + (d4 + 1) * PROWV + colb) =
                make_short4(f2bf(r0.y), f2bf(r1.y), f2bf(r2.y), f2bf(r3.y));
            *(short4*)(sVT + (d4 + 2) * PROWV + colb) =
                make_short4(f2bf(r0.z), f2bf(r1.z), f2bf(r2.z), f2bf(r3.z));
            *(short4*)(sVT + (d4 + 3) * PROWV + colb) =
                make_short4(f2bf(r0.w), f2bf(r1.w), f2bf(r2.w), f2bf(r3.w));
        }
        if (tid < PANEL) sMask[tid] = Mb[j0 + tid] ? 0.f : 1.f;
        __syncthreads();

        #pragma unroll
        for (int jt = 0; jt < 8; jt++) {
            const short* kr = sK + (jt * 16 + c) * PROWK + g * 8;
            bf16x8 kb0 = *(const bf16x8*)(kr);
            bf16x8 kb1 = *(const bf16x8*)(kr + 32);
            f32x4 acc = {0.f, 0.f, 0.f, 0.f};
            acc = MFMA16(qa0, kb0, acc);
            acc = MFMA16(qa1, kb1, acc);
            const float em = sMask[jt * 16 + c];
            #pragma unroll
            for (int r = 0; r < 4; r++)
                sPw[(g * 4 + r) * PROWP + jt * 16 + c] =
                    f2bf(__expf(acc[r] * scl) * em * scv[r]);
        }
        #pragma unroll
        for (int ks = 0; ks < 4; ks++) {
            bf16x8 af = *(const bf16x8*)(sPw + c * PROWP + ks * 32 + g * 8);
            #pragma unroll
            for (int nt = 0; nt < 4; nt++) {
                const int d = nt * 16 + c;
                const int gp = g ^ ((d >> 2) & 3);
                bf16x8 bfrag = *(const bf16x8*)(sVT + d * PROWV + ks * 32 + gp * 8);
                pv[nt] = MFMA16(af, bfrag, pv[nt]);
            }
        }
        const size_t rowBase = (size_t)b * SLEN + i0w;
        #pragma unroll
        for (int it = 0; it < 8; it++) {
            const int idx = it * 64 + l;
            const int row = idx >> 5, col4 = idx & 31;
            const unsigned short* pp = (const unsigned short*)sPw + row * PROWP + col4 * 4;
            ushort4 p4 = *(const ushort4*)(pp);
            float4 o = {bf2f(p4.x), bf2f(p4.y), bf2f(p4.z), bf2f(p4.w)};
            *(float4*)(outAttn + (rowBase + row) * SLEN + j0 + col4 * 4) = o;
        }
        __syncthreads();
    }

    #pragma unroll
    for (int nt = 0; nt < 4; nt++) {
        #pragma unroll
        for (int r = 0; r < 4; r++)
            outCtx[((size_t)b * SLEN + i0w + g * 4 + r) * DIM + nt * 16 + c] = pv[nt][r];
    }
}

extern "C" void kernel_launch(void* const* d_in, const int* in_sizes, int n_in,
                              void* d_out, int out_size, void* d_ws, size_t ws_size,
                              hipStream_t stream) {
    const float* Q = (const float*)d_in[0];
    const float* K = (const float*)d_in[1];
    const float* V = (const float*)d_in[2];
    const int*   M = (const int*)d_in[3];
    float* outCtx  = (float*)d_out;
    float* outAttn = (float*)d_out + (size_t)NBATCH * SLEN * DIM;
    dim3 grid(NBATCH * (SLEN / TQ));   // 512 blocks

    const size_t nElem = (size_t)NBATCH * SLEN * DIM;      // 2,097,152
    const size_t wsNeed = nElem * 2 * sizeof(short);       // 8 MB
    if (d_ws != nullptr && ws_size >= wsNeed) {
        short* Kws  = (short*)d_ws;
        short* VTws = Kws + nElem;
        preconvert_kernel<<<dim3(NBATCH * NPANEL), 256, 0, stream>>>(K, V, Kws, VTws);
        sdpa_kernel<<<grid, NTHR, 0, stream>>>(Q, Kws, VTws, M, outCtx, outAttn);
    } else {
        sdpa_kernel_fb<<<grid, NTHR, 0, stream>>>(Q, K, V, M, outCtx, outAttn);
    }
}